// Round 1
// baseline (3682.947 us; speedup 1.0000x reference)
//
#include <hip/hip_runtime.h>

#define B_SZ 16384
#define D_SZ 1024
#define H_SZ 2048
#define C_SZ 128
#define T_STEPS 20

// ---------------- K0: transpose W2 [C,H] -> W2t [H,C] ----------------
__global__ void k_transpose_w2(const float* __restrict__ W2, float* __restrict__ W2t) {
    int idx = blockIdx.x * blockDim.x + threadIdx.x;   // 0 .. H*C-1
    int h = idx >> 7;        // /128
    int c = idx & 127;
    W2t[idx] = W2[(size_t)c * H_SZ + h];
}

// ---------------- K1: i1 = x @ W1^T + b1, fused 20-step layer-1 LIF ----------------
// 64x64 tile, BK=16, 256 threads, 4x4 accum per thread.
// Epilogue: simulate u1 dynamics per element, emit 20-bit spike mask, popcount -> atomic.
__global__ __launch_bounds__(256) void k_gemm1_sim(
    const float* __restrict__ x, const float* __restrict__ W1,
    const float* __restrict__ b1, unsigned int* __restrict__ masks,
    unsigned int* __restrict__ spike_count)
{
    __shared__ float As[16][68];
    __shared__ float Bs[16][68];
    const int tid  = threadIdx.x;
    const int bm0  = blockIdx.x * 64;   // rows of x (b)
    const int bn0  = blockIdx.y * 64;   // rows of W1 (h)
    const int lrow = tid >> 2;          // 0..63
    const int lk   = (tid & 3) << 2;    // 0,4,8,12
    const int tx   = tid & 15;
    const int ty   = tid >> 4;
    const int r0   = ty << 2;
    const int c0   = tx << 2;

    float acc[4][4] = {};
    const float* xg = x  + (size_t)(bm0 + lrow) * D_SZ + lk;
    const float* wg = W1 + (size_t)(bn0 + lrow) * D_SZ + lk;

    for (int k0 = 0; k0 < D_SZ; k0 += 16) {
        float4 av = *reinterpret_cast<const float4*>(xg + k0);
        float4 bv = *reinterpret_cast<const float4*>(wg + k0);
        __syncthreads();
        As[lk + 0][lrow] = av.x; As[lk + 1][lrow] = av.y;
        As[lk + 2][lrow] = av.z; As[lk + 3][lrow] = av.w;
        Bs[lk + 0][lrow] = bv.x; Bs[lk + 1][lrow] = bv.y;
        Bs[lk + 2][lrow] = bv.z; Bs[lk + 3][lrow] = bv.w;
        __syncthreads();
        #pragma unroll
        for (int kk = 0; kk < 16; ++kk) {
            float4 a4 = *reinterpret_cast<const float4*>(&As[kk][r0]);
            float4 b4 = *reinterpret_cast<const float4*>(&Bs[kk][c0]);
            float aa[4], bb[4];
            aa[0] = a4.x; aa[1] = a4.y; aa[2] = a4.z; aa[3] = a4.w;
            bb[0] = b4.x; bb[1] = b4.y; bb[2] = b4.z; bb[3] = b4.w;
            #pragma unroll
            for (int i = 0; i < 4; ++i)
                #pragma unroll
                for (int j = 0; j < 4; ++j)
                    acc[i][j] = fmaf(aa[i], bb[j], acc[i][j]);
        }
    }

    // epilogue: bias + 20-step LIF, emit masks
    float bb1[4];
    {
        float4 t = *reinterpret_cast<const float4*>(b1 + bn0 + c0);
        bb1[0] = t.x; bb1[1] = t.y; bb1[2] = t.z; bb1[3] = t.w;
    }
    int local_spikes = 0;
    #pragma unroll
    for (int i = 0; i < 4; ++i) {
        unsigned int mrow[4];
        #pragma unroll
        for (int j = 0; j < 4; ++j) {
            float i1 = acc[i][j] + bb1[j];
            float u = 0.0f;
            unsigned int m = 0;
            #pragma unroll
            for (int t = 0; t < T_STEPS; ++t) {
                u = __fadd_rn(__fmul_rn(0.9f, u), i1);   // match np: separate mul, add
                if (u >= 1.0f) { m |= (1u << t); u = 0.0f; }
            }
            mrow[j] = m;
            local_spikes += __popc(m);
        }
        *reinterpret_cast<uint4*>(masks + (size_t)(bm0 + r0 + i) * H_SZ + bn0 + c0) =
            make_uint4(mrow[0], mrow[1], mrow[2], mrow[3]);
    }
    // wave reduction of spike count, one atomic per wave
    #pragma unroll
    for (int off = 32; off > 0; off >>= 1)
        local_spikes += __shfl_down(local_spikes, off);
    if ((tid & 63) == 0)
        atomicAdd(spike_count, (unsigned int)local_spikes);
}

// ---------------- K2: layer 2. One wave per batch row; lane owns cols c=lane, lane+64 ----------------
// inj2[t][c] accumulated over h with mask-bit -> float fma; then 20-step u2 LIF.
__global__ __launch_bounds__(256) void k_layer2(
    const unsigned int* __restrict__ masks, const float* __restrict__ W2t,
    const float* __restrict__ b2, float* __restrict__ out)
{
    __shared__ float Ws[64][C_SZ];      // 32 KB tile of W2t
    const int tid  = threadIdx.x;
    const int wv   = tid >> 6;          // wave in block: 0..3
    const int lane = tid & 63;
    const int b    = blockIdx.x * 4 + wv;
    const unsigned int* mrow = masks + (size_t)b * H_SZ;

    float acc0[T_STEPS] = {};
    float acc1[T_STEPS] = {};

    for (int ht = 0; ht < H_SZ; ht += 64) {
        __syncthreads();
        const float4* src = reinterpret_cast<const float4*>(W2t + (size_t)ht * C_SZ);
        float4* dst = reinterpret_cast<float4*>(&Ws[0][0]);
        #pragma unroll
        for (int i = 0; i < 8; ++i)
            dst[tid + i * 256] = src[tid + i * 256];
        __syncthreads();
        #pragma unroll 2
        for (int hh = 0; hh < 64; ++hh) {
            unsigned int m = (unsigned int)__builtin_amdgcn_readfirstlane((int)mrow[ht + hh]);
            float w0 = Ws[hh][lane];
            float w1 = Ws[hh][lane + 64];
            #pragma unroll
            for (int t = 0; t < T_STEPS; ++t) {
                float st = (float)((m >> t) & 1u);
                acc0[t] = fmaf(st, w0, acc0[t]);
                acc1[t] = fmaf(st, w1, acc1[t]);
            }
        }
    }

    // layer-2 LIF sim + logits write (cnt/20 via IEEE division to match ref)
    {
        float u = 0.0f; int cnt = 0;
        const float bias = b2[lane];
        #pragma unroll
        for (int t = 0; t < T_STEPS; ++t) {
            float X = acc0[t] + bias;                 // (s1@W2.T + b2) first
            u = __fadd_rn(__fmul_rn(0.9f, u), X);     // beta*u2 + X
            if (u >= 1.0f) { cnt++; u = 0.0f; }
        }
        out[(size_t)b * C_SZ + lane] = (float)cnt / 20.0f;
    }
    {
        float u = 0.0f; int cnt = 0;
        const float bias = b2[lane + 64];
        #pragma unroll
        for (int t = 0; t < T_STEPS; ++t) {
            float X = acc1[t] + bias;
            u = __fadd_rn(__fmul_rn(0.9f, u), X);
            if (u >= 1.0f) { cnt++; u = 0.0f; }
        }
        out[(size_t)b * C_SZ + lane + 64] = (float)cnt / 20.0f;
    }
}

// ---------------- K3: mean_spikes = total / (B * T) ----------------
__global__ void k_finalize(const unsigned int* __restrict__ spike_count, float* __restrict__ out) {
    out[(size_t)B_SZ * C_SZ] = (float)(*spike_count) / (float)((size_t)B_SZ * T_STEPS);
}

extern "C" void kernel_launch(void* const* d_in, const int* in_sizes, int n_in,
                              void* d_out, int out_size, void* d_ws, size_t ws_size,
                              hipStream_t stream) {
    const float* x  = (const float*)d_in[0];
    const float* W1 = (const float*)d_in[1];
    const float* b1 = (const float*)d_in[2];
    const float* W2 = (const float*)d_in[3];
    const float* b2 = (const float*)d_in[4];
    float* out = (float*)d_out;

    char* ws = (char*)d_ws;
    const size_t mask_bytes = (size_t)B_SZ * H_SZ * sizeof(unsigned int);   // 128 MB
    const size_t w2t_bytes  = (size_t)H_SZ * C_SZ * sizeof(float);          // 1 MB
    unsigned int* masks   = (unsigned int*)ws;
    float*        W2t     = (float*)(ws + mask_bytes);
    unsigned int* counter = (unsigned int*)(ws + mask_bytes + w2t_bytes);

    hipMemsetAsync(counter, 0, sizeof(unsigned int), stream);

    k_transpose_w2<<<(H_SZ * C_SZ) / 256, 256, 0, stream>>>(W2, W2t);

    dim3 g1(B_SZ / 64, H_SZ / 64);
    k_gemm1_sim<<<g1, 256, 0, stream>>>(x, W1, b1, masks, counter);

    k_layer2<<<B_SZ / 4, 256, 0, stream>>>(masks, W2t, b2, out);

    k_finalize<<<1, 1, 0, stream>>>(counter, out);
}

// Round 2
// 2282.606 us; speedup vs baseline: 1.6135x; 1.6135x over previous
//
#include <hip/hip_runtime.h>
#include <hip/hip_bf16.h>

#define B_SZ 16384
#define D_SZ 1024
#define H_SZ 2048
#define C_SZ 128
#define T_STEPS 20

typedef __attribute__((ext_vector_type(4))) float f32x4;
typedef __attribute__((ext_vector_type(8))) short bf16x8;

// ---------------- K0: split W2 [C,H] fp32 -> 3 bf16 planes [s][C][H] ----------------
__global__ void k_w2split(const float* __restrict__ W2, unsigned short* __restrict__ W2p) {
    int idx = blockIdx.x * blockDim.x + threadIdx.x;   // c*H + h, 0..262143
    float w = W2[idx];
    __hip_bfloat16 hi = __float2bfloat16(w);
    float fhi = __bfloat162float(hi);
    __hip_bfloat16 mid = __float2bfloat16(w - fhi);
    float fmid = __bfloat162float(mid);
    __hip_bfloat16 lo = __float2bfloat16(w - fhi - fmid);
    W2p[idx]               = __bfloat16_as_ushort(hi);
    W2p[262144 + idx]      = __bfloat16_as_ushort(mid);
    W2p[524288 + idx]      = __bfloat16_as_ushort(lo);
}

// ---------------- K1: i1 = x @ W1^T + b1, fused 20-step layer-1 LIF ----------------
__global__ __launch_bounds__(256) void k_gemm1_sim(
    const float* __restrict__ x, const float* __restrict__ W1,
    const float* __restrict__ b1, unsigned int* __restrict__ masks,
    unsigned int* __restrict__ spike_count)
{
    __shared__ float As[16][68];
    __shared__ float Bs[16][68];
    const int tid  = threadIdx.x;
    const int bm0  = blockIdx.x * 64;   // rows of x (b)
    const int bn0  = blockIdx.y * 64;   // rows of W1 (h)
    const int lrow = tid >> 2;          // 0..63
    const int lk   = (tid & 3) << 2;    // 0,4,8,12
    const int tx   = tid & 15;
    const int ty   = tid >> 4;
    const int r0   = ty << 2;
    const int c0   = tx << 2;

    float acc[4][4] = {};
    const float* xg = x  + (size_t)(bm0 + lrow) * D_SZ + lk;
    const float* wg = W1 + (size_t)(bn0 + lrow) * D_SZ + lk;

    for (int k0 = 0; k0 < D_SZ; k0 += 16) {
        float4 av = *reinterpret_cast<const float4*>(xg + k0);
        float4 bv = *reinterpret_cast<const float4*>(wg + k0);
        __syncthreads();
        As[lk + 0][lrow] = av.x; As[lk + 1][lrow] = av.y;
        As[lk + 2][lrow] = av.z; As[lk + 3][lrow] = av.w;
        Bs[lk + 0][lrow] = bv.x; Bs[lk + 1][lrow] = bv.y;
        Bs[lk + 2][lrow] = bv.z; Bs[lk + 3][lrow] = bv.w;
        __syncthreads();
        #pragma unroll
        for (int kk = 0; kk < 16; ++kk) {
            float4 a4 = *reinterpret_cast<const float4*>(&As[kk][r0]);
            float4 b4 = *reinterpret_cast<const float4*>(&Bs[kk][c0]);
            float aa[4], bb[4];
            aa[0] = a4.x; aa[1] = a4.y; aa[2] = a4.z; aa[3] = a4.w;
            bb[0] = b4.x; bb[1] = b4.y; bb[2] = b4.z; bb[3] = b4.w;
            #pragma unroll
            for (int i = 0; i < 4; ++i)
                #pragma unroll
                for (int j = 0; j < 4; ++j)
                    acc[i][j] = fmaf(aa[i], bb[j], acc[i][j]);
        }
    }

    float bb1[4];
    {
        float4 t = *reinterpret_cast<const float4*>(b1 + bn0 + c0);
        bb1[0] = t.x; bb1[1] = t.y; bb1[2] = t.z; bb1[3] = t.w;
    }
    int local_spikes = 0;
    #pragma unroll
    for (int i = 0; i < 4; ++i) {
        unsigned int mrow[4];
        #pragma unroll
        for (int j = 0; j < 4; ++j) {
            float i1 = acc[i][j] + bb1[j];
            float u = 0.0f;
            unsigned int m = 0;
            #pragma unroll
            for (int t = 0; t < T_STEPS; ++t) {
                u = __fadd_rn(__fmul_rn(0.9f, u), i1);
                if (u >= 1.0f) { m |= (1u << t); u = 0.0f; }
            }
            mrow[j] = m;
            local_spikes += __popc(m);
        }
        *reinterpret_cast<uint4*>(masks + (size_t)(bm0 + r0 + i) * H_SZ + bn0 + c0) =
            make_uint4(mrow[0], mrow[1], mrow[2], mrow[3]);
    }
    #pragma unroll
    for (int off = 32; off > 0; off >>= 1)
        local_spikes += __shfl_down(local_spikes, off);
    if ((tid & 63) == 0)
        atomicAdd(spike_count, (unsigned int)local_spikes);
}

// ---------------- K2: layer 2 via bf16 3-split MFMA ----------------
// Block: 256 thr = 4 waves, out tile 16 rows x 128 cols (wave w: cols w*32..w*32+31).
// For each 32-wide h-tile: stage W2 planes in LDS, expand spike bits -> bf16 A frags
// in-register per timestep, 6 MFMAs per t (3 splits x 2 n-tiles). 20 t accumulators.
__global__ __launch_bounds__(256, 2) void k_layer2_mfma(
    const unsigned int* __restrict__ masks,
    const unsigned short* __restrict__ W2p,   // 3 planes [C][H] bf16 bits
    const float* __restrict__ b2,
    float* __restrict__ out)
{
    __shared__ unsigned short Bs[3][C_SZ][32];   // 24 KB
    const int tid  = threadIdx.x;
    const int w    = tid >> 6;
    const int lane = tid & 63;
    const int l15  = lane & 15;        // A-row / B-col / D-col selector
    const int g    = lane >> 4;        // k-group / D-row group
    const int b0   = blockIdx.x * 16;
    const int colbase = w * 32;

    f32x4 acc[2][T_STEPS];
    #pragma unroll
    for (int n = 0; n < 2; ++n)
        #pragma unroll
        for (int t = 0; t < T_STEPS; ++t)
            acc[n][t] = (f32x4){0.f, 0.f, 0.f, 0.f};

    const unsigned int* mrow = masks + (size_t)(b0 + l15) * H_SZ;

    for (int kt = 0; kt < 64; ++kt) {
        const int h0 = kt * 32;
        // per-lane 8 mask words: h = h0 + g*8 .. +7 (row b0+l15)
        const uint4* mp = reinterpret_cast<const uint4*>(mrow + h0 + g * 8);
        uint4 mA = mp[0];
        uint4 mB = mp[1];

        __syncthreads();
        // stage Bs[s][c][0..31] = W2p[s][c][h0..h0+31]; 24KB, 6 x 16B per thread, linear
        {
            char* bsl = reinterpret_cast<char*>(&Bs[0][0][0]);
            #pragma unroll
            for (int it = 0; it < 6; ++it) {
                int o  = it * 4096 + tid * 16;       // byte offset in Bs
                int s  = o >> 13;
                int c  = (o >> 6) & 127;
                int kk = (o & 63) >> 1;
                const uint4* src = reinterpret_cast<const uint4*>(
                    W2p + (size_t)(s * C_SZ + c) * H_SZ + h0 + kk);
                *reinterpret_cast<uint4*>(bsl + o) = *src;
            }
        }
        __syncthreads();

        // B fragments: lane l15 = col, g*8.. = k
        bf16x8 bf[3][2];
        #pragma unroll
        for (int s = 0; s < 3; ++s)
            #pragma unroll
            for (int nt = 0; nt < 2; ++nt)
                bf[s][nt] = *reinterpret_cast<const bf16x8*>(&Bs[s][colbase + nt * 16 + l15][g * 8]);

        #pragma unroll
        for (int t = 0; t < T_STEPS; ++t) {
            union { bf16x8 v; unsigned int u[4]; } A;
            A.u[0] = (((mA.x >> t) & 1u) | (((mA.y >> t) & 1u) << 16)) * 0x3F80u;
            A.u[1] = (((mA.z >> t) & 1u) | (((mA.w >> t) & 1u) << 16)) * 0x3F80u;
            A.u[2] = (((mB.x >> t) & 1u) | (((mB.y >> t) & 1u) << 16)) * 0x3F80u;
            A.u[3] = (((mB.z >> t) & 1u) | (((mB.w >> t) & 1u) << 16)) * 0x3F80u;
            #pragma unroll
            for (int s = 0; s < 3; ++s) {
                acc[0][t] = __builtin_amdgcn_mfma_f32_16x16x32_bf16(A.v, bf[s][0], acc[0][t], 0, 0, 0);
                acc[1][t] = __builtin_amdgcn_mfma_f32_16x16x32_bf16(A.v, bf[s][1], acc[1][t], 0, 0, 0);
            }
        }
    }

    // epilogue: C/D layout col = lane&15, row = g*4 + reg
    #pragma unroll
    for (int nt = 0; nt < 2; ++nt) {
        const int c = colbase + nt * 16 + l15;
        const float bias = b2[c];
        #pragma unroll
        for (int j = 0; j < 4; ++j) {
            const int br = b0 + g * 4 + j;
            float u = 0.0f; int cnt = 0;
            #pragma unroll
            for (int t = 0; t < T_STEPS; ++t) {
                float X = acc[nt][t][j] + bias;
                u = __fadd_rn(__fmul_rn(0.9f, u), X);
                if (u >= 1.0f) { cnt++; u = 0.0f; }
            }
            out[(size_t)br * C_SZ + c] = (float)cnt / 20.0f;
        }
    }
}

// ---------------- K3: mean_spikes = total / (B * T) ----------------
__global__ void k_finalize(const unsigned int* __restrict__ spike_count, float* __restrict__ out) {
    out[(size_t)B_SZ * C_SZ] = (float)(*spike_count) / (float)((size_t)B_SZ * T_STEPS);
}

extern "C" void kernel_launch(void* const* d_in, const int* in_sizes, int n_in,
                              void* d_out, int out_size, void* d_ws, size_t ws_size,
                              hipStream_t stream) {
    const float* x  = (const float*)d_in[0];
    const float* W1 = (const float*)d_in[1];
    const float* b1 = (const float*)d_in[2];
    const float* W2 = (const float*)d_in[3];
    const float* b2 = (const float*)d_in[4];
    float* out = (float*)d_out;

    char* ws = (char*)d_ws;
    const size_t mask_bytes = (size_t)B_SZ * H_SZ * sizeof(unsigned int);   // 128 MB
    const size_t w2p_bytes  = (size_t)3 * C_SZ * H_SZ * sizeof(unsigned short); // 1.5 MB
    unsigned int*   masks   = (unsigned int*)ws;
    unsigned short* W2p     = (unsigned short*)(ws + mask_bytes);
    unsigned int*   counter = (unsigned int*)(ws + mask_bytes + w2p_bytes);

    hipMemsetAsync(counter, 0, sizeof(unsigned int), stream);

    k_w2split<<<(C_SZ * H_SZ) / 256, 256, 0, stream>>>(W2, W2p);

    dim3 g1(B_SZ / 64, H_SZ / 64);
    k_gemm1_sim<<<g1, 256, 0, stream>>>(x, W1, b1, masks, counter);

    k_layer2_mfma<<<B_SZ / 16, 256, 0, stream>>>(masks, W2p, b2, out);

    k_finalize<<<1, 1, 0, stream>>>(counter, out);
}

// Round 3
// 620.693 us; speedup vs baseline: 5.9336x; 3.6775x over previous
//
#include <hip/hip_runtime.h>
#include <hip/hip_bf16.h>

#define B_SZ 16384
#define D_SZ 1024
#define H_SZ 2048
#define C_SZ 128
#define T_STEPS 20

typedef __attribute__((ext_vector_type(4))) float f32x4;
typedef __attribute__((ext_vector_type(8))) short bf16x8;

__device__ __forceinline__ void gl_lds16(const void* g, void* l) {
    __builtin_amdgcn_global_load_lds(
        (const __attribute__((address_space(1))) unsigned int*)g,
        (__attribute__((address_space(3))) unsigned int*)l, 16, 0, 0);
}

__device__ __forceinline__ unsigned int lif_mask(float i1) {
    float u = 0.0f;
    unsigned int m = 0;
    #pragma unroll
    for (int t = 0; t < T_STEPS; ++t) {
        u = __fadd_rn(__fmul_rn(0.9f, u), i1);   // match np: separate mul, add
        if (u >= 1.0f) { m |= (1u << t); u = 0.0f; }
    }
    return m;
}

// ---------------- split W1 [H][D] fp32 -> 2 bf16 planes [2][H][D] (RNE hi, RNE mid) ----
__global__ void k_w1split(const float* __restrict__ W1, unsigned short* __restrict__ w1s) {
    int idx = blockIdx.x * blockDim.x + threadIdx.x;
    float w = W1[idx];
    __hip_bfloat16 hi = __float2bfloat16(w);
    float fh = __bfloat162float(hi);
    __hip_bfloat16 mid = __float2bfloat16(w - fh);
    w1s[idx] = __bfloat16_as_ushort(hi);
    w1s[(size_t)H_SZ * D_SZ + idx] = __bfloat16_as_ushort(mid);
}

// ---------------- split W2 [C][H] fp32 -> 2 bf16 planes [2][C][H] ----------------
__global__ void k_w2split(const float* __restrict__ W2, unsigned short* __restrict__ W2p) {
    int idx = blockIdx.x * blockDim.x + threadIdx.x;
    float w = W2[idx];
    __hip_bfloat16 hi = __float2bfloat16(w);
    float fh = __bfloat162float(hi);
    __hip_bfloat16 mid = __float2bfloat16(w - fh);
    W2p[idx] = __bfloat16_as_ushort(hi);
    W2p[(size_t)C_SZ * H_SZ + idx] = __bfloat16_as_ushort(mid);
}

// x trunc-hi / RNE-mid split of a float pair into two packed bf16x2 words
#define SPLIT2(fe, fo, HW, MW) { \
    unsigned ue = __float_as_uint(fe), uo = __float_as_uint(fo); \
    HW = (uo & 0xffff0000u) | (ue >> 16); \
    float re = (fe) - __uint_as_float(ue & 0xffff0000u); \
    float ro = (fo) - __uint_as_float(uo & 0xffff0000u); \
    MW = (unsigned)__bfloat16_as_ushort(__float2bfloat16(re)) | \
         ((unsigned)__bfloat16_as_ushort(__float2bfloat16(ro)) << 16); }

// ---------------- K1: i1 = x @ W1^T + b1 via 2-split bf16 MFMA, fused LIF -> masks ----
// A = W1 (M dim = h), B = x (N dim = b). 128x128 tile, 4 waves (2x2), BK=32.
// LDS rows are 128 B ([row][plane][32 bf16]); XOR swizzle byte ^= (row&7)<<4.
// W1 staged via global_load_lds (linear dest, pre-swizzled source);
// x staged via reg: load fp32, split to hi/mid, swizzled ds_write.
__global__ __launch_bounds__(256) void k_gemm1_mfma(
    const float* __restrict__ x,
    const unsigned short* __restrict__ w1s,   // [2][H][D]
    const float* __restrict__ b1,
    unsigned short* __restrict__ M16,
    unsigned char* __restrict__ M4,
    unsigned int* __restrict__ spike_count)
{
    __shared__ char lds[32768];   // [0,16K): W1 tile, [16K,32K): x tile
    const int tid  = threadIdx.x;
    const int wv   = tid >> 6;
    const int lane = tid & 63;
    const int l15  = lane & 15;
    const int g    = lane >> 4;
    const int wr   = wv >> 1;      // h-half
    const int wc   = wv & 1;       // b-half
    const int hb0  = blockIdx.x * 128;
    const int bb0  = blockIdx.y * 128;

    const int ar   = tid >> 1;            // x staging row (b within tile)
    const int ac0  = (tid & 1) * 16;      // col base (floats)
    const float* xrow = x + (size_t)(bb0 + ar) * D_SZ + ac0;
    const int asw   = (ar & 7) << 4;
    const int lbase = 16384 + ar * 128 + ac0 * 2;

    f32x4 acc[4][4];
    #pragma unroll
    for (int i = 0; i < 4; ++i)
        #pragma unroll
        for (int j = 0; j < 4; ++j)
            acc[i][j] = (f32x4){0.f, 0.f, 0.f, 0.f};

    for (int k0 = 0; k0 < D_SZ; k0 += 32) {
        float4 av0 = *reinterpret_cast<const float4*>(xrow + k0);
        float4 av1 = *reinterpret_cast<const float4*>(xrow + k0 + 4);
        float4 av2 = *reinterpret_cast<const float4*>(xrow + k0 + 8);
        float4 av3 = *reinterpret_cast<const float4*>(xrow + k0 + 12);
        __syncthreads();
        // W1 planes -> LDS[0,16K): linear dest, source from inverse-swizzled index
        #pragma unroll
        for (int i = 0; i < 4; ++i) {
            int o   = i * 4096 + wv * 1024 + lane * 16;
            int col = o >> 7;
            int p   = o ^ ((col & 7) << 4);
            int s   = (p >> 6) & 1;
            int kk  = (p & 63) >> 1;
            const unsigned short* gsrc =
                w1s + ((size_t)s * H_SZ + hb0 + col) * D_SZ + k0 + kk;
            gl_lds16(gsrc, lds + (i * 4096 + wv * 1024));
        }
        // x: split + swizzled LDS write
        {
            uint4 hwv, hwv2, mwv, mwv2;
            SPLIT2(av0.x, av0.y, hwv.x,  mwv.x);
            SPLIT2(av0.z, av0.w, hwv.y,  mwv.y);
            SPLIT2(av1.x, av1.y, hwv.z,  mwv.z);
            SPLIT2(av1.z, av1.w, hwv.w,  mwv.w);
            SPLIT2(av2.x, av2.y, hwv2.x, mwv2.x);
            SPLIT2(av2.z, av2.w, hwv2.y, mwv2.y);
            SPLIT2(av3.x, av3.y, hwv2.z, mwv2.z);
            SPLIT2(av3.z, av3.w, hwv2.w, mwv2.w);
            *reinterpret_cast<uint4*>(lds + ((lbase)      ^ asw)) = hwv;
            *reinterpret_cast<uint4*>(lds + ((lbase + 16) ^ asw)) = hwv2;
            *reinterpret_cast<uint4*>(lds + ((lbase + 64) ^ asw)) = mwv;
            *reinterpret_cast<uint4*>(lds + ((lbase + 80) ^ asw)) = mwv2;
        }
        __syncthreads();

        bf16x8 Xh[4], Xm[4];
        #pragma unroll
        for (int n = 0; n < 4; ++n) {
            int c  = wc * 64 + n * 16 + l15;
            int sw = (c & 7) << 4;
            Xh[n] = *reinterpret_cast<const bf16x8*>(lds + (16384 + ((c * 128 + g * 16) ^ sw)));
            Xm[n] = *reinterpret_cast<const bf16x8*>(lds + (16384 + ((c * 128 + 64 + g * 16) ^ sw)));
        }
        #pragma unroll
        for (int m = 0; m < 4; ++m) {
            int r  = wr * 64 + m * 16 + l15;
            int sw = (r & 7) << 4;
            bf16x8 Wh = *reinterpret_cast<const bf16x8*>(lds + ((r * 128 + g * 16) ^ sw));
            bf16x8 Wm = *reinterpret_cast<const bf16x8*>(lds + ((r * 128 + 64 + g * 16) ^ sw));
            #pragma unroll
            for (int n = 0; n < 4; ++n) {
                acc[m][n] = __builtin_amdgcn_mfma_f32_16x16x32_bf16(Wh, Xh[n], acc[m][n], 0, 0, 0);
                acc[m][n] = __builtin_amdgcn_mfma_f32_16x16x32_bf16(Wh, Xm[n], acc[m][n], 0, 0, 0);
                acc[m][n] = __builtin_amdgcn_mfma_f32_16x16x32_bf16(Wm, Xh[n], acc[m][n], 0, 0, 0);
            }
        }
    }

    // epilogue: D row (g*4+j) = h (A index), D col (l15) = b (B index)
    int spikes = 0;
    #pragma unroll
    for (int m = 0; m < 4; ++m) {
        const int h0l = hb0 + wr * 64 + m * 16 + g * 4;
        float4 bias = *reinterpret_cast<const float4*>(b1 + h0l);
        #pragma unroll
        for (int n = 0; n < 4; ++n) {
            const int b = bb0 + wc * 64 + n * 16 + l15;
            unsigned mk0 = lif_mask(acc[m][n][0] + bias.x);
            unsigned mk1 = lif_mask(acc[m][n][1] + bias.y);
            unsigned mk2 = lif_mask(acc[m][n][2] + bias.z);
            unsigned mk3 = lif_mask(acc[m][n][3] + bias.w);
            spikes += __popc(mk0) + __popc(mk1) + __popc(mk2) + __popc(mk3);
            *reinterpret_cast<uint2*>(M16 + (size_t)b * H_SZ + h0l) =
                make_uint2((mk0 & 0xffffu) | (mk1 << 16),
                           (mk2 & 0xffffu) | (mk3 << 16));
            *reinterpret_cast<unsigned int*>(M4 + (size_t)b * H_SZ + h0l) =
                (mk0 >> 16) | ((mk1 >> 16) << 8) | ((mk2 >> 16) << 16) | ((mk3 >> 16) << 24);
        }
    }
    #pragma unroll
    for (int off = 32; off > 0; off >>= 1)
        spikes += __shfl_down(spikes, off);
    if (lane == 0)
        atomicAdd(spike_count, (unsigned int)spikes);
}

// ---------------- K2: layer 2 via 2-split bf16 MFMA ----------------
// Block: 4 waves, out tile 16 b-rows x 128 cols (wave w: cols w*32..+31).
// Spike bits expanded in-register from u16/u8 masks; 20 fp32x4 accumulators.
__global__ __launch_bounds__(256) __attribute__((amdgpu_waves_per_eu(2, 2)))
void k_layer2_mfma(
    const unsigned short* __restrict__ M16,
    const unsigned char* __restrict__ M4,
    const unsigned short* __restrict__ W2p,   // [2][C][H]
    const float* __restrict__ b2,
    float* __restrict__ out)
{
    __shared__ unsigned short Bs[2][C_SZ][40];   // padded rows: ~2-way banks
    const int tid  = threadIdx.x;
    const int w    = tid >> 6;
    const int lane = tid & 63;
    const int l15  = lane & 15;
    const int g    = lane >> 4;
    const int b0   = blockIdx.x * 16;
    const int colbase = w * 32;

    f32x4 acc[2][T_STEPS];
    #pragma unroll
    for (int n = 0; n < 2; ++n)
        #pragma unroll
        for (int t = 0; t < T_STEPS; ++t)
            acc[n][t] = (f32x4){0.f, 0.f, 0.f, 0.f};

    const unsigned short* m16row = M16 + (size_t)(b0 + l15) * H_SZ;
    const unsigned char*  m4row  = M4  + (size_t)(b0 + l15) * H_SZ;

    for (int kt = 0; kt < 64; ++kt) {
        const int h0 = kt * 32;
        uint4 w16 = *reinterpret_cast<const uint4*>(m16row + h0 + g * 8);
        uint2 w4;
        {
            const uint2* p4 = reinterpret_cast<const uint2*>(m4row + h0 + g * 8);
            w4 = *p4;
        }

        __syncthreads();
        #pragma unroll
        for (int it = 0; it < 4; ++it) {
            int o  = it * 4096 + tid * 16;
            int s  = o >> 13;
            int c  = (o >> 6) & 127;
            int kk = (o & 63) >> 1;
            *reinterpret_cast<uint4*>(&Bs[s][c][kk]) =
                *reinterpret_cast<const uint4*>(W2p + ((size_t)s * C_SZ + c) * H_SZ + h0 + kk);
        }
        __syncthreads();

        bf16x8 bf[2][2];
        #pragma unroll
        for (int s = 0; s < 2; ++s)
            #pragma unroll
            for (int nt = 0; nt < 2; ++nt)
                bf[s][nt] = *reinterpret_cast<const bf16x8*>(&Bs[s][colbase + nt * 16 + l15][g * 8]);

        #pragma unroll
        for (int t = 0; t < T_STEPS; ++t) {
            union { bf16x8 v; unsigned int u[4]; } A;
            if (t < 16) {
                A.u[0] = ((w16.x >> t) & 0x10001u) * 0x3F80u;
                A.u[1] = ((w16.y >> t) & 0x10001u) * 0x3F80u;
                A.u[2] = ((w16.z >> t) & 0x10001u) * 0x3F80u;
                A.u[3] = ((w16.w >> t) & 0x10001u) * 0x3F80u;
            } else {
                const int tt = t - 16;
                unsigned x0 = (w4.x >> tt)        & 0x101u;
                unsigned x1 = (w4.x >> (16 + tt)) & 0x101u;
                unsigned x2 = (w4.y >> tt)        & 0x101u;
                unsigned x3 = (w4.y >> (16 + tt)) & 0x101u;
                A.u[0] = ((x0 * 0x0101u) & 0x10001u) * 0x3F80u;
                A.u[1] = ((x1 * 0x0101u) & 0x10001u) * 0x3F80u;
                A.u[2] = ((x2 * 0x0101u) & 0x10001u) * 0x3F80u;
                A.u[3] = ((x3 * 0x0101u) & 0x10001u) * 0x3F80u;
            }
            acc[0][t] = __builtin_amdgcn_mfma_f32_16x16x32_bf16(A.v, bf[0][0], acc[0][t], 0, 0, 0);
            acc[0][t] = __builtin_amdgcn_mfma_f32_16x16x32_bf16(A.v, bf[1][0], acc[0][t], 0, 0, 0);
            acc[1][t] = __builtin_amdgcn_mfma_f32_16x16x32_bf16(A.v, bf[0][1], acc[1][t], 0, 0, 0);
            acc[1][t] = __builtin_amdgcn_mfma_f32_16x16x32_bf16(A.v, bf[1][1], acc[1][t], 0, 0, 0);
        }
    }

    // epilogue: col = l15 (+nt*16+colbase), row = g*4 + reg
    #pragma unroll
    for (int nt = 0; nt < 2; ++nt) {
        const int c = colbase + nt * 16 + l15;
        const float bias = b2[c];
        #pragma unroll
        for (int j = 0; j < 4; ++j) {
            const int br = b0 + g * 4 + j;
            float u = 0.0f; int cnt = 0;
            #pragma unroll
            for (int t = 0; t < T_STEPS; ++t) {
                float X = acc[nt][t][j] + bias;
                u = __fadd_rn(__fmul_rn(0.9f, u), X);
                if (u >= 1.0f) { cnt++; u = 0.0f; }
            }
            out[(size_t)br * C_SZ + c] = (float)cnt / 20.0f;
        }
    }
}

// ---------------- K3: mean_spikes = total / (B * T) ----------------
__global__ void k_finalize(const unsigned int* __restrict__ spike_count, float* __restrict__ out) {
    out[(size_t)B_SZ * C_SZ] = (float)(*spike_count) / (float)((size_t)B_SZ * T_STEPS);
}

extern "C" void kernel_launch(void* const* d_in, const int* in_sizes, int n_in,
                              void* d_out, int out_size, void* d_ws, size_t ws_size,
                              hipStream_t stream) {
    const float* x  = (const float*)d_in[0];
    const float* W1 = (const float*)d_in[1];
    const float* b1 = (const float*)d_in[2];
    const float* W2 = (const float*)d_in[3];
    const float* b2 = (const float*)d_in[4];
    float* out = (float*)d_out;

    char* ws = (char*)d_ws;
    const size_t m16_b = (size_t)B_SZ * H_SZ * 2;        // 67.1 MB
    const size_t m4_b  = (size_t)B_SZ * H_SZ;            // 33.6 MB
    const size_t w1s_b = (size_t)2 * H_SZ * D_SZ * 2;    // 8.4 MB
    const size_t w2p_b = (size_t)2 * C_SZ * H_SZ * 2;    // 1.05 MB
    unsigned short* M16 = (unsigned short*)ws;
    unsigned char*  M4  = (unsigned char*)(ws + m16_b);
    unsigned short* w1s = (unsigned short*)(ws + m16_b + m4_b);
    unsigned short* W2p = (unsigned short*)(ws + m16_b + m4_b + w1s_b);
    unsigned int* counter = (unsigned int*)(ws + m16_b + m4_b + w1s_b + w2p_b);

    hipMemsetAsync(counter, 0, sizeof(unsigned int), stream);

    k_w1split<<<(H_SZ * D_SZ) / 256, 256, 0, stream>>>(W1, w1s);
    k_w2split<<<(C_SZ * H_SZ) / 256, 256, 0, stream>>>(W2, W2p);

    dim3 g1(H_SZ / 128, B_SZ / 128);   // (16, 128)
    k_gemm1_mfma<<<g1, 256, 0, stream>>>(x, w1s, b1, M16, M4, counter);

    k_layer2_mfma<<<B_SZ / 16, 256, 0, stream>>>(M16, M4, W2p, b2, out);

    k_finalize<<<1, 1, 0, stream>>>(counter, out);
}